// Round 17
// baseline (251.443 us; speedup 1.0000x reference)
//
#include <hip/hip_runtime.h>

// ---------------------------------------------------------------------------
// Transformer block on MI355X (gfx950), bf16 MFMA pipeline, fp32 residual/LN.
//   x:[2,2048,1024]  LN over T (ddof=1) -> fused QK+V^T GEMM -> causal flash
//   attn (r10 structure; nc==1 blocks finalize in-place: +resid, x2, LN2
//   partials) + merge(+LN2 partial, qb>=8 only) -> fused LN -> MLP -> +resid
// r17: GEMMs reverted to r14 (2-barrier counted vmcnt, BK=64 — best known);
//      light attn blocks skip the merge pass entirely.
// ---------------------------------------------------------------------------

typedef __bf16 bf16x8 __attribute__((ext_vector_type(8)));
typedef float f32x4 __attribute__((ext_vector_type(4)));
typedef unsigned short u16;
typedef u16 u16x8 __attribute__((ext_vector_type(8)));
typedef u16 u16x4 __attribute__((ext_vector_type(4)));

#define MFMA16 __builtin_amdgcn_mfma_f32_16x16x32_bf16

__device__ __forceinline__ u16 f2bf(float f) {  // native v_cvt (RNE)
  return __builtin_bit_cast(u16, (__bf16)f);
}
__device__ __forceinline__ float bf2f(u16 u) {
  return __builtin_bit_cast(float, (unsigned)u << 16);
}
__device__ __forceinline__ bf16x8 ldbf8(const u16* p) {
  return __builtin_bit_cast(bf16x8, *reinterpret_cast<const u16x8*>(p));
}
// async global->LDS, 16B per lane, dest = wave-uniform base + lane*16
__device__ __forceinline__ void gll16(const void* g, void* l) {
  __builtin_amdgcn_global_load_lds((const __attribute__((address_space(1))) void*)g,
                                   (__attribute__((address_space(3))) void*)l, 16, 0, 0);
}
template <int N>
__device__ __forceinline__ void wait_vm() {
  if constexpr (N == 0)      asm volatile("s_waitcnt vmcnt(0)" ::: "memory");
  else if constexpr (N == 6) asm volatile("s_waitcnt vmcnt(6)" ::: "memory");
  else if constexpr (N == 8) asm volatile("s_waitcnt vmcnt(8)" ::: "memory");
  else                       asm volatile("s_waitcnt vmcnt(16)" ::: "memory");
}
__device__ __forceinline__ void barrier_raw() {
  asm volatile("" ::: "memory");
  __builtin_amdgcn_s_barrier();
  asm volatile("" ::: "memory");
}
// slot offset table for (qb, chunk): 80 slots per bh
__device__ __forceinline__ int qb_off(int qb) {
  if (qb < 8)  return qb;
  if (qb < 16) return 8 + (qb - 8) * 2;
  if (qb < 24) return 24 + (qb - 16) * 3;
  return 48 + (qb - 24) * 4;
}

// ---------------- fused prep: weight transposes + LN1 partials -------------
// blocks [0,768): Wq/Wk/Wv -> wqkvt (Wq scaled).  [768,2816): W1/W2 -> w1t/w2t.
// [2816,3072): LN1 partial sums of x.
__global__ __launch_bounds__(256) void prep_fused(const float* __restrict__ Wq,
                                                  const float* __restrict__ Wk,
                                                  const float* __restrict__ Wv,
                                                  const float* __restrict__ W1,
                                                  const float* __restrict__ W2,
                                                  const float* __restrict__ x,
                                                  u16* __restrict__ wqkvt,
                                                  u16* __restrict__ w1t,
                                                  u16* __restrict__ w2t,
                                                  float2* __restrict__ part,
                                                  float scale) {
  __shared__ alignas(16) char smem[64 * 65 * 4];
  const int id = blockIdx.x;
  if (id < 2816) {  // a 64x64 f32->bf16 transpose tile
    const float* in;
    u16* out;
    int K, N, kb, nb, roff = 0;
    float sc = 1.0f;
    if (id < 768) {
      const int z = id >> 8, rem = id & 255;
      in = z == 0 ? Wq : (z == 1 ? Wk : Wv);
      if (z == 0) sc = scale;
      out = wqkvt;
      K = 1024; N = 64;
      kb = rem & 15; nb = 0;
      roff = z * 1024 + (rem >> 4) * 64;   // head row offset
      in += (size_t)(rem >> 4) * 1024 * 64;
    } else if (id < 1792) {
      const int i2 = id - 768;
      in = W1; out = w1t; K = 1024; N = 4096; kb = i2 & 15; nb = i2 >> 4;
    } else {
      const int i2 = id - 1792;
      in = W2; out = w2t; K = 4096; N = 1024; kb = i2 >> 4; nb = i2 & 15;
    }
    float (*tile)[65] = (float(*)[65])smem;
    const int k0 = kb * 64, n0 = nb * 64;
    const int c = threadIdx.x & 63, rg = threadIdx.x >> 6;
#pragma unroll
    for (int i = 0; i < 16; ++i) {
      int r = rg * 16 + i;
      tile[r][c] = in[(size_t)(k0 + r) * N + n0 + c];
    }
    __syncthreads();
#pragma unroll
    for (int i = 0; i < 16; ++i) {
      int nl = rg * 16 + i;
      out[(size_t)(roff + n0 + nl) * K + k0 + c] = f2bf(tile[c][nl] * sc);
    }
  } else {  // LN1 partial sums
    const int idm = id - 2816;
    const int bx = idm & 31, by = idm >> 5;
    const int b = bx >> 4, c0 = (bx & 15) * 64;
    const int c = c0 + (threadIdx.x & 63), tg = threadIdx.x >> 6;
    const int t0 = by * 256 + tg * 64;
    float s = 0.f, sq = 0.f;
    const float* p = x + (size_t)(b * 2048 + t0) * 1024 + c;
#pragma unroll 8
    for (int i = 0; i < 64; ++i) {
      float v = p[(size_t)i * 1024];
      s += v; sq += v * v;
    }
    float* ss = (float*)smem;
    float* sb = ss + 256;
    ss[threadIdx.x] = s; sb[threadIdx.x] = sq;
    __syncthreads();
    if (threadIdx.x < 64) {
      s  = ss[threadIdx.x] + ss[threadIdx.x + 64] + ss[threadIdx.x + 128] + ss[threadIdx.x + 192];
      sq = sb[threadIdx.x] + sb[threadIdx.x + 64] + sb[threadIdx.x + 128] + sb[threadIdx.x + 192];
      part[(size_t)(b * 1024 + c) * 8 + by] = make_float2(s, sq);
    }
  }
}

// ---------------- fused LayerNorm stats + apply ----------------------------
template <int NC>
__global__ __launch_bounds__(256) void ln_stats_apply(const float* __restrict__ x,
                                                      const float2* __restrict__ part,
                                                      const float* __restrict__ g,
                                                      const float* __restrict__ be,
                                                      u16* __restrict__ out) {
  const int slab = blockIdx.x * 64;
  const int y0 = blockIdx.y * 256;
  const int b = blockIdx.z;
  const int tid = threadIdx.x;
  __shared__ float2 sst[64];
  __shared__ float sg[64], sbe[64];
  if (tid < 64) {
    const int c = slab + tid;
    float s = 0.f, sq = 0.f;
#pragma unroll
    for (int i = 0; i < NC; ++i) {
      float2 v = part[(size_t)(b * 1024 + c) * NC + i];
      s += v.x; sq += v.y;
    }
    const float mean = s * (1.0f / 2048.0f);
    const float var = (sq - 2048.0f * mean * mean) * (1.0f / 2047.0f);  // ddof=1
    sst[tid] = make_float2(mean, rsqrtf(var + 1e-5f));
    sg[tid] = g[c];
    sbe[tid] = be[c];
  }
  __syncthreads();
  const int c4 = (tid & 15) * 4;   // col within slab
  const int r0 = tid >> 4;         // row group 0..15
  const size_t base = ((size_t)(b * 2048 + y0)) * 1024 + slab + c4;
#pragma unroll
  for (int it = 0; it < 16; ++it) {
    const int row = r0 * 16 + it;
    float4 xv = *reinterpret_cast<const float4*>(x + base + (size_t)row * 1024);
    float vs[4] = {xv.x, xv.y, xv.z, xv.w};
    u16x4 o;
#pragma unroll
    for (int j = 0; j < 4; ++j) {
      float2 st = sst[c4 + j];
      o[j] = f2bf(sg[c4 + j] * (vs[j] - st.x) * st.y + sbe[c4 + j]);
    }
    *reinterpret_cast<u16x4*>(out + base + (size_t)row * 1024) = o;
  }
}

// ---------------- GEMM core: C = A[M,K] x Bt[N,K]^T ------------------------
// 256 threads / 4 waves (2x2), wave tile 64 x WTN. BM=128, BN=2*WTN, BK=64.
// Double-buffered, counted vmcnt (r14 form). LDS XOR-swizzled at 16B granules.
// EPI 0: store bf16.  1: +bias, ReLU, bf16.  2: +bias +resid, f32.
template <int WTN, int EPI>
__device__ __forceinline__ void gemm_core(const u16* __restrict__ A,
                                          const u16* __restrict__ Bt,
                                          u16* __restrict__ outb,
                                          float* __restrict__ outf,
                                          const float* __restrict__ bias,
                                          const float* __restrict__ resid,
                                          int N, int K, int m0, int n0) {
  constexpr int BM = 128, BN = 2 * WTN;
  constexpr int NI = WTN / 16;          // 4 or 2
  constexpr int BCH = BN / 8;           // B chunks
  constexpr int LPW = (16 + BCH) / 4;   // gll16 per wave per stage (8 or 6)
  __shared__ alignas(16) u16 sA[2][BM * 64];
  __shared__ alignas(16) u16 sB[2][BN * 64];
  const int tid = threadIdx.x, lane = tid & 63, wid = tid >> 6;
  const int wm = (wid >> 1) * 64, wn = (wid & 1) * WTN;
  const int lr = lane & 15, lg = lane >> 4;
  const int srow = lane >> 3;                 // row within 8-row chunk
  const int sgr = (lane & 7) ^ srow;          // pre-swizzled source granule
  const int x7 = lr & 7;                      // read-side swizzle key
  f32x4 acc[4][NI] = {};

  auto stage = [&](int buf, int k0) {
#pragma unroll
    for (int i = 0; i < LPW; ++i) {
      const int c = wid * LPW + i;
      if (c < 16) {
        const int r = c * 8 + srow;
        gll16(A + (size_t)(m0 + r) * K + k0 + sgr * 8, &sA[buf][c * 512]);
      } else {
        const int r = (c - 16) * 8 + srow;
        gll16(Bt + (size_t)(n0 + r) * K + k0 + sgr * 8, &sB[buf][(c - 16) * 512]);
      }
    }
  };

  const int nsteps = K >> 6;
  stage(0, 0);
  int cur = 0;
  for (int t = 0; t < nsteps; ++t) {
    if (t + 1 < nsteps) {
      stage(cur ^ 1, (t + 1) * 64);  // prefetch stays in flight across barriers
      wait_vm<LPW>();                // tile t's loads (oldest) have landed
    } else {
      wait_vm<0>();
    }
    barrier_raw();
    bf16x8 af[4][2], bfr[NI][2];
#pragma unroll
    for (int mi = 0; mi < 4; ++mi)
#pragma unroll
      for (int kk = 0; kk < 2; ++kk)
        af[mi][kk] = ldbf8(&sA[cur][(wm + mi * 16 + lr) * 64 + (((kk * 4 + lg) ^ x7) * 8)]);
#pragma unroll
    for (int ni = 0; ni < NI; ++ni)
#pragma unroll
      for (int kk = 0; kk < 2; ++kk)
        bfr[ni][kk] = ldbf8(&sB[cur][(wn + ni * 16 + lr) * 64 + (((kk * 4 + lg) ^ x7) * 8)]);
#pragma unroll
    for (int kk = 0; kk < 2; ++kk)
#pragma unroll
      for (int mi = 0; mi < 4; ++mi)
#pragma unroll
        for (int ni = 0; ni < NI; ++ni)
          acc[mi][ni] = MFMA16(af[mi][kk], bfr[ni][kk], acc[mi][ni], 0, 0, 0);
    barrier_raw();                   // WAR: reads done before next overwrite
    cur ^= 1;
  }

#pragma unroll
  for (int mi = 0; mi < 4; ++mi)
#pragma unroll
    for (int ni = 0; ni < NI; ++ni)
#pragma unroll
      for (int r = 0; r < 4; ++r) {
        const int row = m0 + wm + mi * 16 + lg * 4 + r;   // C/D: row=(lane>>4)*4+reg
        const int col = n0 + wn + ni * 16 + lr;           //      col=lane&15
        float v = acc[mi][ni][r];
        if (EPI == 0) {
          outb[(size_t)row * N + col] = f2bf(v);
        } else if (EPI == 1) {
          v += bias[col];
          v = fmaxf(v, 0.f);
          outb[(size_t)row * N + col] = f2bf(v);
        } else {
          v += bias[col] + resid[(size_t)row * N + col];
          outf[(size_t)row * N + col] = v;
        }
      }
}

// standalone GEMM (MLP1/MLP2) with XCD swizzle
template <int WTN, int EPI, int MINW>
__global__ __launch_bounds__(256, MINW) void gemm_kernel(const u16* __restrict__ A,
                                                         const u16* __restrict__ Bt,
                                                         u16* __restrict__ outb,
                                                         float* __restrict__ outf,
                                                         const float* __restrict__ bias,
                                                         const float* __restrict__ resid,
                                                         int N, int K) {
  constexpr int BN = 2 * WTN;
  const int gx = gridDim.x;
  const int nwg = gx * gridDim.y;
  int bid = blockIdx.y * gx + blockIdx.x;
  bid = (bid & 7) * (nwg >> 3) + (bid >> 3);
  const int n0 = (bid % gx) * BN, m0 = (bid / gx) * 128;
  gemm_core<WTN, EPI>(A, Bt, outb, outf, bias, resid, N, K, m0, n0);
}

// fused QK + V^T GEMM: blocks [0,512) -> QK (M=4096,N=2048); [512,768) -> VT
// (M=1024,N=4096). Both BN=128, K=1024. XCD swizzle within each segment.
__global__ __launch_bounds__(256, 2) void gemm_qkvt(const u16* __restrict__ hbuf,
                                                    const u16* __restrict__ wqkvt,
                                                    u16* __restrict__ qkb,
                                                    u16* __restrict__ vtb) {
  int bid = blockIdx.x;
  const u16 *A, *Bt;
  u16* outb;
  int N, m0, n0;
  if (bid < 512) {
    bid = (bid & 7) * 64 + (bid >> 3);
    A = hbuf; Bt = wqkvt; outb = qkb; N = 2048;
    n0 = (bid % 16) * 128; m0 = (bid / 16) * 128;
  } else {
    int b2 = bid - 512;
    b2 = (b2 & 7) * 32 + (b2 >> 3);
    A = wqkvt + 2048 * 1024; Bt = hbuf; outb = vtb; N = 4096;
    n0 = (b2 % 32) * 128; m0 = (b2 / 32) * 128;
  }
  gemm_core<64, 0>(A, Bt, outb, nullptr, nullptr, nullptr, N, 1024, m0, n0);
}

// ---------------- causal flash attention: split-s partial pass -------------
// r10 structure. nc==1 blocks (qb<8, full s-range) finalize in-place:
// normalize, +residual, write x2, LN2 column partials (re-using dead LDS).
// qk: bf16 [4096 tok][2048] (Q|K per head), Q pre-scaled to exp2 domain.
// vt: bf16 [1024 hd][4096 tok].
__global__ __launch_bounds__(256, 6) void attn_partial(const u16* __restrict__ qk,
                                                       const u16* __restrict__ vt,
                                                       const float* __restrict__ x,
                                                       float* __restrict__ x2,
                                                       u16* __restrict__ Opart,
                                                       float2* __restrict__ ml,
                                                       float2* __restrict__ part) {
  const int xr = 79 - (int)blockIdx.x;  // heavy (long-range) blocks first
  int qb, ch, nc;
  if (xr < 8)       { qb = xr;                ch = 0;            nc = 1; }
  else if (xr < 24) { qb = 8 + ((xr - 8) >> 1);  ch = (xr - 8) & 1;  nc = 2; }
  else if (xr < 48) { qb = 16 + (xr - 24) / 3;   ch = (xr - 24) % 3; nc = 3; }
  else              { qb = 24 + ((xr - 48) >> 2); ch = (xr - 48) & 3; nc = 4; }
  const int nt_tot = qb + 1;
  const int t0 = (ch * nt_tot) / nc;
  const int t1 = ((ch + 1) * nt_tot) / nc;
  const int bh = blockIdx.y, b = bh >> 4, h = bh & 15;
  const int slot = bh * 80 + xr;
  const int q0 = qb * 64;
  const int tid = threadIdx.x, lane = tid & 63, w = tid >> 6;
  const int lr = lane & 15, lg = lane >> 4;
  // 24 KB carved LDS: sK 8KB | sV 8KB | sP 8KB; fbuf (floats) aliases all
  // of it in the nc==1 epilogue (safe: loop-ending barrier makes them dead).
  __shared__ alignas(16) char smem[24576];
  u16* const sK = (u16*)smem;
  u16* const sV = (u16*)(smem + 8192);
  u16* const sPw = (u16*)(smem + 16384) + w * (16 * 64);

  const size_t qrow = (size_t)(b * 2048 + q0 + w * 16 + lr) * 2048 + h * 64;
  const bf16x8 aq0 = ldbf8(qk + qrow + lg * 8);
  const bf16x8 aq1 = ldbf8(qk + qrow + 32 + lg * 8);

  float m_i[4], l_i[4];   // l_i: PER-LANE partial sums (reduced in epilogue)
  f32x4 acc[4];
#pragma unroll
  for (int r = 0; r < 4; ++r) { m_i[r] = -1e30f; l_i[r] = 0.f; }
#pragma unroll
  for (int dn = 0; dn < 4; ++dn) acc[dn] = f32x4{0.f, 0.f, 0.f, 0.f};

  auto stage = [&](int s0) {
#pragma unroll
    for (int i = 0; i < 2; ++i) {
      const int c = w * 2 + i;
      const int g = c * 64 + lane;
      const int row = g >> 3;
      const int cs = (g & 7) ^ (row & 7);
      gll16(qk + (size_t)(b * 2048 + s0 + row) * 2048 + 1024 + h * 64 + cs * 8,
            &sK[c * 512]);
      gll16(vt + (size_t)(h * 64 + row) * 4096 + b * 2048 + s0 + cs * 8,
            &sV[c * 512]);
    }
  };

  for (int t = t0; t < t1; ++t) {
    stage(t * 64);
    wait_vm<0>();
    barrier_raw();   // tile visible to all waves

    f32x4 sf[4];
    __builtin_amdgcn_s_setprio(1);
#pragma unroll
    for (int sn = 0; sn < 4; ++sn) {  // S[16q x 64s] = Q . K^T (exp2 domain)
      const int row = sn * 16 + lr;
      const int x7 = lr & 7;
      bf16x8 k0f = ldbf8(&sK[row * 64 + ((lg ^ x7) * 8)]);
      bf16x8 k1f = ldbf8(&sK[row * 64 + (((4 + lg) ^ x7) * 8)]);
      f32x4 z = {0.f, 0.f, 0.f, 0.f};
      z = MFMA16(aq0, k0f, z, 0, 0, 0);
      z = MFMA16(aq1, k1f, z, 0, 0, 0);
      sf[sn] = z;
    }
    __builtin_amdgcn_s_setprio(0);

    if (t == nt_tot - 1) {  // causal mask (last tile only)
      const int qlb = w * 16 + lg * 4;
#pragma unroll
      for (int sn = 0; sn < 4; ++sn)
#pragma unroll
        for (int r = 0; r < 4; ++r)
          if (sn * 16 + lr > qlb + r) sf[sn][r] = -1e30f;
    }

    // defer-max fast path: full reduce+rescale only when growth > 8
    float pm[4];
    bool need = false;
#pragma unroll
    for (int r = 0; r < 4; ++r) {
      pm[r] = fmaxf(fmaxf(sf[0][r], sf[1][r]), fmaxf(sf[2][r], sf[3][r]));
      need = need || (pm[r] > m_i[r] + 8.f);
    }
    if (__any(need)) {
#pragma unroll
      for (int r = 0; r < 4; ++r) {
        float mx = pm[r];
        mx = fmaxf(mx, __shfl_xor(mx, 1, 16));
        mx = fmaxf(mx, __shfl_xor(mx, 2, 16));
        mx = fmaxf(mx, __shfl_xor(mx, 4, 16));
        mx = fmaxf(mx, __shfl_xor(mx, 8, 16));
        const float mnew = fmaxf(m_i[r], mx);
        const float al = exp2f(m_i[r] - mnew);
        l_i[r] *= al;
        acc[0][r] *= al; acc[1][r] *= al; acc[2][r] *= al; acc[3][r] *= al;
        m_i[r] = mnew;
      }
    }

    // P = exp2(S - m); per-lane l accumulation; swizzled P store
    const int x7p = lr & 7;
#pragma unroll
    for (int r = 0; r < 4; ++r) {
      const float p0 = exp2f(sf[0][r] - m_i[r]), p1 = exp2f(sf[1][r] - m_i[r]);
      const float p2 = exp2f(sf[2][r] - m_i[r]), p3 = exp2f(sf[3][r] - m_i[r]);
      l_i[r] += (p0 + p1) + (p2 + p3);
      const int prow = lg * 4 + r;
      const int pb = prow * 64, px = prow & 7;
      sPw[pb + (((lr >> 3) ^ px) * 8) + (lr & 7)]       = f2bf(p0);
      sPw[pb + (((2 + (lr >> 3)) ^ px) * 8) + (lr & 7)] = f2bf(p1);
      sPw[pb + (((4 + (lr >> 3)) ^ px) * 8) + (lr & 7)] = f2bf(p2);
      sPw[pb + (((6 + (lr >> 3)) ^ px) * 8) + (lr & 7)] = f2bf(p3);
    }

    // O += P . V   (wave-local P; compiler inserts lgkmcnt for the RAW)
    const bf16x8 pa0 = ldbf8(&sPw[lr * 64 + ((lg ^ x7p) * 8)]);
    const bf16x8 pa1 = ldbf8(&sPw[lr * 64 + (((4 + lg) ^ x7p) * 8)]);
    __builtin_amdgcn_s_setprio(1);
#pragma unroll
    for (int dn = 0; dn < 4; ++dn) {
      const int row = dn * 16 + lr;
      bf16x8 v0f = ldbf8(&sV[row * 64 + ((lg ^ x7p) * 8)]);
      bf16x8 v1f = ldbf8(&sV[row * 64 + (((4 + lg) ^ x7p) * 8)]);
      acc[dn] = MFMA16(pa0, v0f, acc[dn], 0, 0, 0);
      acc[dn] = MFMA16(pa1, v1f, acc[dn], 0, 0, 0);
    }
    __builtin_amdgcn_s_setprio(0);
    barrier_raw();  // WAR guard before next stage overwrites
  }

  const int rbase = w * 16 + lg * 4;
  if (nc == 1) {
    // full s-range covered: finalize here (normalize, +resid, LN2 partials)
    float* fbuf = (float*)smem;   // 64x65 floats; sK/sV/sP dead (loop barrier)
#pragma unroll
    for (int r = 0; r < 4; ++r) {
      float ls = l_i[r];
      ls += __shfl_xor(ls, 1, 16);
      ls += __shfl_xor(ls, 2, 16);
      ls += __shfl_xor(ls, 4, 16);
      ls += __shfl_xor(ls, 8, 16);
      const float inv = 1.0f / ls;
      const int row = rbase + r;
#pragma unroll
      for (int dn = 0; dn < 4; ++dn) {
        const size_t idx = ((size_t)(b * 2048 + q0 + row)) * 1024 + h * 64 + dn * 16 + lr;
        const float val = x[idx] + acc[dn][r] * inv;
        x2[idx] = val;
        fbuf[row * 65 + dn * 16 + lr] = val;
      }
    }
    __syncthreads();
    if (tid < 64) {  // LN2 column partials over this block's 64 t-rows
      float s = 0.f, sq = 0.f;
#pragma unroll 8
      for (int t2 = 0; t2 < 64; ++t2) {
        float v = fbuf[t2 * 65 + tid];
        s += v; sq += v * v;
      }
      part[(size_t)(b * 1024 + h * 64 + tid) * 32 + qb] = make_float2(s, sq);
    }
  } else {
    // partial epilogue: reduce per-lane l, write unnormalized O (bf16) + (m,l)
#pragma unroll
    for (int r = 0; r < 4; ++r) {
      float ls = l_i[r];
      ls += __shfl_xor(ls, 1, 16);
      ls += __shfl_xor(ls, 2, 16);
      ls += __shfl_xor(ls, 4, 16);
      ls += __shfl_xor(ls, 8, 16);
      const int row = rbase + r;
      if (lr == 0) ml[(size_t)slot * 64 + row] = make_float2(m_i[r], ls);
#pragma unroll
      for (int dn = 0; dn < 4; ++dn)
        Opart[((size_t)slot * 64 + row) * 64 + dn * 16 + lr] = f2bf(acc[dn][r]);
    }
  }
}

// ---------------- attention merge + residual + LN2 partial sums ------------
// qb >= 8 only (qb < 8 finalized inside attn_partial).
__global__ __launch_bounds__(256) void attn_merge_ln(const u16* __restrict__ Opart,
                                                     const float2* __restrict__ ml,
                                                     const float* __restrict__ x,
                                                     float* __restrict__ x2,
                                                     float2* __restrict__ part) {
  const int qb = 8 + (int)blockIdx.x;
  const int bh = blockIdx.y, b = bh >> 4, h = bh & 15;
  const int nc = (qb >> 3) + 1;
  const size_t slot0 = (size_t)bh * 80 + qb_off(qb);
  const int tid = threadIdx.x;
  const int row = tid >> 2, d0 = (tid & 3) * 16;
  __shared__ float red[64][65];

  float wgt[4];
  float mmax = -1e30f, lsum = 0.f;
  for (int i = 0; i < nc; ++i) {
    float2 v = ml[(slot0 + i) * 64 + row];
    wgt[i] = v.x;
    mmax = fmaxf(mmax, v.x);
  }
  for (int i = 0; i < nc; ++i) {
    float2 v = ml[(slot0 + i) * 64 + row];
    wgt[i] = exp2f(wgt[i] - mmax);
    lsum += wgt[i] * v.y;
  }
  const float inv = 1.0f / lsum;

#pragma unroll
  for (int half = 0; half < 2; ++half) {
    const int d = d0 + half * 8;
    float o[8] = {0.f, 0.f, 0.f, 0.f, 0.f, 0.f, 0.f, 0.f};
    for (int i = 0; i < nc; ++i) {
      u16x8 v = *reinterpret_cast<const u16x8*>(&Opart[((slot0 + i) * 64 + row) * 64 + d]);
#pragma unroll
      for (int jj = 0; jj < 8; ++jj) o[jj] += wgt[i] * bf2f(v[jj]);
    }
    const size_t idx = ((size_t)(b * 2048 + qb * 64 + row)) * 1024 + h * 64 + d;
    float4 x0 = *reinterpret_cast<const float4*>(x + idx);
    float4 x1 = *reinterpret_cast<const float4*>(x + idx + 4);
    float4 o0 = make_float4(x0.x + o[0] * inv, x0.y + o[1] * inv, x0.z + o[2] * inv, x0.w + o[3] * inv);
    float4 o1 = make_float4(x1.x + o[4] * inv, x1.y + o[5] * inv, x1.z + o[6] * inv, x1.w + o[7] * inv);
    *reinterpret_cast<float4*>(x2 + idx) = o0;
    *reinterpret_cast<float4*>(x2 + idx + 4) = o1;
    red[row][d + 0] = o0.x; red[row][d + 1] = o0.y; red[row][d + 2] = o0.z; red[row][d + 3] = o0.w;
    red[row][d + 4] = o1.x; red[row][d + 5] = o1.y; red[row][d + 6] = o1.z; red[row][d + 7] = o1.w;
  }
  __syncthreads();
  if (tid < 64) {  // column-reduce over the 64 t-rows
    float s = 0.f, sq = 0.f;
#pragma unroll 8
    for (int t = 0; t < 64; ++t) {
      float v = red[t][tid];
      s += v; sq += v * v;
    }
    part[(size_t)(b * 1024 + h * 64 + tid) * 32 + qb] = make_float2(s, sq);
  }
}

// ---------------------------------------------------------------------------
extern "C" void kernel_launch(void* const* d_in, const int* in_sizes, int n_in,
                              void* d_out, int out_size, void* d_ws, size_t ws_size,
                              hipStream_t stream) {
  const float* x   = (const float*)d_in[0];
  const float* Wq  = (const float*)d_in[1];
  const float* Wk  = (const float*)d_in[2];
  const float* Wv  = (const float*)d_in[3];
  const float* W1  = (const float*)d_in[4];
  const float* b1  = (const float*)d_in[5];
  const float* W2  = (const float*)d_in[6];
  const float* b2  = (const float*)d_in[7];
  const float* g1  = (const float*)d_in[8];
  const float* be1 = (const float*)d_in[9];
  const float* g2  = (const float*)d_in[10];
  const float* be2 = (const float*)d_in[11];
  float* out = (float*)d_out;

  char* ws = (char*)d_ws;
  size_t off = 0;
  auto alloc = [&](size_t bytes) { char* p = ws + off; off += (bytes + 255) & ~(size_t)255; return p; };
  u16*    qkb   = (u16*)alloc(4096ull * 2048 * 2);   // [tok][Q|K]          16MB
  u16*    vtb   = (u16*)alloc(1024ull * 4096 * 2);   // [hd][tok]            8MB
  (void)alloc(4096ull * 1024 * 2);                   // h1 overflow region   8MB
  u16*    h1    = qkb;                               // MLP1 out aliases qk+vt+overflow (32MB)
  float*  x2    = (float*)alloc(4096ull * 1024 * 4); // x + attn            16MB
  u16*    hbuf  = (u16*)alloc(4096ull * 1024 * 2);   // LN outputs           8MB
  u16*    wqkvt = (u16*)alloc(3072ull * 1024 * 2);
  u16*    w1t   = (u16*)alloc(4096ull * 1024 * 2);
  u16*    w2t   = (u16*)alloc(1024ull * 4096 * 2);
  float2* part  = (float2*)alloc(2048ull * 32 * 8);  // LN partials (8 or 32 chunks)
  float2* stats = (float2*)alloc(2048ull * 8);       // (unused, kept for layout)
  u16*    Opart = (u16*)alloc(32ull * 80 * 64 * 64 * 2);   // ~21MB
  float2* ml    = (float2*)alloc(32ull * 80 * 64 * 8);     // ~1.3MB
  (void)ws_size; (void)in_sizes; (void)n_in; (void)out_size; (void)stats;

  // fused prep: weight transposes (Wq scaled by C^-0.5*log2e) + LN1 partials
  const float SC = 0.03125f * 1.44269504088896341f;
  prep_fused<<<3072, 256, 0, stream>>>(Wq, Wk, Wv, W1, W2, x, wqkvt, w1t, w2t, part, SC);

  // LN1: fused stats+apply -> hbuf (bf16)
  ln_stats_apply<8><<<dim3(16, 8, 2), 256, 0, stream>>>(x, part, g1, be1, hbuf);

  // fused QK GEMM (-> qkb [4096][2048]) + V^T GEMM (-> vtb [1024][4096])
  gemm_qkvt<<<768, 256, 0, stream>>>(hbuf, wqkvt, qkb, vtb);

  // attention: split-s partials (nc==1 blocks finalize in-place), then merge
  attn_partial<<<dim3(80, 32), 256, 0, stream>>>(qkb, vtb, x, x2, Opart, ml, part);
  attn_merge_ln<<<dim3(24, 32), 256, 0, stream>>>(Opart, ml, x, x2, part);

  // LN2: fused stats+apply -> hbuf (bf16)
  ln_stats_apply<32><<<dim3(16, 8, 2), 256, 0, stream>>>(x2, part, g2, be2, hbuf);

  // MLP1: relu(h @ W1 + b1) -> h1 (bf16 [4096][4096])   (BN=128)
  gemm_kernel<64, 1, 2><<<dim3(32, 32), 256, 0, stream>>>(hbuf, w1t, h1, nullptr, b1, nullptr, 4096, 1024);

  // MLP2: x2 + h1 @ W2 + b2 -> out (f32)   (BN=64)
  gemm_kernel<32, 2, 3><<<dim3(16, 32), 256, 0, stream>>>(h1, w2t, nullptr, out, b2, x2, 1024, 4096);
}

// Round 18
// 223.428 us; speedup vs baseline: 1.1254x; 1.1254x over previous
//
#include <hip/hip_runtime.h>

// ---------------------------------------------------------------------------
// Transformer block on MI355X (gfx950), bf16 MFMA pipeline, fp32 residual/LN.
//   x:[2,2048,1024]  LN over T (ddof=1) -> fused QK+V^T GEMM -> causal flash
//   attn (r10: split-s, single-buffer, 6 blocks/CU) + merge(+LN2 partial)
//   -> fused LN stats+apply -> MLP -> +resid
// r18: full revert to r14 (223.3 us best). r17's nc==1 fusion regressed via
//      launch_bounds-forced VGPR spill (40 VGPR, 2.3x HBM traffic).
// ---------------------------------------------------------------------------

typedef __bf16 bf16x8 __attribute__((ext_vector_type(8)));
typedef float f32x4 __attribute__((ext_vector_type(4)));
typedef unsigned short u16;
typedef u16 u16x8 __attribute__((ext_vector_type(8)));
typedef u16 u16x4 __attribute__((ext_vector_type(4)));

#define MFMA16 __builtin_amdgcn_mfma_f32_16x16x32_bf16

__device__ __forceinline__ u16 f2bf(float f) {  // native v_cvt (RNE)
  return __builtin_bit_cast(u16, (__bf16)f);
}
__device__ __forceinline__ float bf2f(u16 u) {
  return __builtin_bit_cast(float, (unsigned)u << 16);
}
__device__ __forceinline__ bf16x8 ldbf8(const u16* p) {
  return __builtin_bit_cast(bf16x8, *reinterpret_cast<const u16x8*>(p));
}
// async global->LDS, 16B per lane, dest = wave-uniform base + lane*16
__device__ __forceinline__ void gll16(const void* g, void* l) {
  __builtin_amdgcn_global_load_lds((const __attribute__((address_space(1))) void*)g,
                                   (__attribute__((address_space(3))) void*)l, 16, 0, 0);
}
template <int N>
__device__ __forceinline__ void wait_vm() {
  if constexpr (N == 0)      asm volatile("s_waitcnt vmcnt(0)" ::: "memory");
  else if constexpr (N == 6) asm volatile("s_waitcnt vmcnt(6)" ::: "memory");
  else if constexpr (N == 8) asm volatile("s_waitcnt vmcnt(8)" ::: "memory");
  else                       asm volatile("s_waitcnt vmcnt(16)" ::: "memory");
}
__device__ __forceinline__ void barrier_raw() {
  asm volatile("" ::: "memory");
  __builtin_amdgcn_s_barrier();
  asm volatile("" ::: "memory");
}
// slot offset table for (qb, chunk): 80 slots per bh
__device__ __forceinline__ int qb_off(int qb) {
  if (qb < 8)  return qb;
  if (qb < 16) return 8 + (qb - 8) * 2;
  if (qb < 24) return 24 + (qb - 16) * 3;
  return 48 + (qb - 24) * 4;
}

// ---------------- fused prep: weight transposes + LN1 partials -------------
// blocks [0,768): Wq/Wk/Wv -> wqkvt (Wq scaled).  [768,2816): W1/W2 -> w1t/w2t.
// [2816,3072): LN1 partial sums of x.
__global__ __launch_bounds__(256) void prep_fused(const float* __restrict__ Wq,
                                                  const float* __restrict__ Wk,
                                                  const float* __restrict__ Wv,
                                                  const float* __restrict__ W1,
                                                  const float* __restrict__ W2,
                                                  const float* __restrict__ x,
                                                  u16* __restrict__ wqkvt,
                                                  u16* __restrict__ w1t,
                                                  u16* __restrict__ w2t,
                                                  float2* __restrict__ part,
                                                  float scale) {
  __shared__ alignas(16) char smem[64 * 65 * 4];
  const int id = blockIdx.x;
  if (id < 2816) {  // a 64x64 f32->bf16 transpose tile
    const float* in;
    u16* out;
    int K, N, kb, nb, roff = 0;
    float sc = 1.0f;
    if (id < 768) {
      const int z = id >> 8, rem = id & 255;
      in = z == 0 ? Wq : (z == 1 ? Wk : Wv);
      if (z == 0) sc = scale;
      out = wqkvt;
      K = 1024; N = 64;
      kb = rem & 15; nb = 0;
      roff = z * 1024 + (rem >> 4) * 64;   // head row offset
      in += (size_t)(rem >> 4) * 1024 * 64;
    } else if (id < 1792) {
      const int i2 = id - 768;
      in = W1; out = w1t; K = 1024; N = 4096; kb = i2 & 15; nb = i2 >> 4;
    } else {
      const int i2 = id - 1792;
      in = W2; out = w2t; K = 4096; N = 1024; kb = i2 >> 4; nb = i2 & 15;
    }
    float (*tile)[65] = (float(*)[65])smem;
    const int k0 = kb * 64, n0 = nb * 64;
    const int c = threadIdx.x & 63, rg = threadIdx.x >> 6;
#pragma unroll
    for (int i = 0; i < 16; ++i) {
      int r = rg * 16 + i;
      tile[r][c] = in[(size_t)(k0 + r) * N + n0 + c];
    }
    __syncthreads();
#pragma unroll
    for (int i = 0; i < 16; ++i) {
      int nl = rg * 16 + i;
      out[(size_t)(roff + n0 + nl) * K + k0 + c] = f2bf(tile[c][nl] * sc);
    }
  } else {  // LN1 partial sums
    const int idm = id - 2816;
    const int bx = idm & 31, by = idm >> 5;
    const int b = bx >> 4, c0 = (bx & 15) * 64;
    const int c = c0 + (threadIdx.x & 63), tg = threadIdx.x >> 6;
    const int t0 = by * 256 + tg * 64;
    float s = 0.f, sq = 0.f;
    const float* p = x + (size_t)(b * 2048 + t0) * 1024 + c;
#pragma unroll 8
    for (int i = 0; i < 64; ++i) {
      float v = p[(size_t)i * 1024];
      s += v; sq += v * v;
    }
    float* ss = (float*)smem;
    float* sb = ss + 256;
    ss[threadIdx.x] = s; sb[threadIdx.x] = sq;
    __syncthreads();
    if (threadIdx.x < 64) {
      s  = ss[threadIdx.x] + ss[threadIdx.x + 64] + ss[threadIdx.x + 128] + ss[threadIdx.x + 192];
      sq = sb[threadIdx.x] + sb[threadIdx.x + 64] + sb[threadIdx.x + 128] + sb[threadIdx.x + 192];
      part[(size_t)(b * 1024 + c) * 8 + by] = make_float2(s, sq);
    }
  }
}

// ---------------- fused LayerNorm stats + apply ----------------------------
template <int NC>
__global__ __launch_bounds__(256) void ln_stats_apply(const float* __restrict__ x,
                                                      const float2* __restrict__ part,
                                                      const float* __restrict__ g,
                                                      const float* __restrict__ be,
                                                      u16* __restrict__ out) {
  const int slab = blockIdx.x * 64;
  const int y0 = blockIdx.y * 256;
  const int b = blockIdx.z;
  const int tid = threadIdx.x;
  __shared__ float2 sst[64];
  __shared__ float sg[64], sbe[64];
  if (tid < 64) {
    const int c = slab + tid;
    float s = 0.f, sq = 0.f;
#pragma unroll
    for (int i = 0; i < NC; ++i) {
      float2 v = part[(size_t)(b * 1024 + c) * NC + i];
      s += v.x; sq += v.y;
    }
    const float mean = s * (1.0f / 2048.0f);
    const float var = (sq - 2048.0f * mean * mean) * (1.0f / 2047.0f);  // ddof=1
    sst[tid] = make_float2(mean, rsqrtf(var + 1e-5f));
    sg[tid] = g[c];
    sbe[tid] = be[c];
  }
  __syncthreads();
  const int c4 = (tid & 15) * 4;   // col within slab
  const int r0 = tid >> 4;         // row group 0..15
  const size_t base = ((size_t)(b * 2048 + y0)) * 1024 + slab + c4;
#pragma unroll
  for (int it = 0; it < 16; ++it) {
    const int row = r0 * 16 + it;
    float4 xv = *reinterpret_cast<const float4*>(x + base + (size_t)row * 1024);
    float vs[4] = {xv.x, xv.y, xv.z, xv.w};
    u16x4 o;
#pragma unroll
    for (int j = 0; j < 4; ++j) {
      float2 st = sst[c4 + j];
      o[j] = f2bf(sg[c4 + j] * (vs[j] - st.x) * st.y + sbe[c4 + j]);
    }
    *reinterpret_cast<u16x4*>(out + base + (size_t)row * 1024) = o;
  }
}

// ---------------- GEMM core: C = A[M,K] x Bt[N,K]^T ------------------------
// 256 threads / 4 waves (2x2), wave tile 64 x WTN. BM=128, BN=2*WTN, BK=64.
// Double-buffered, counted vmcnt. LDS XOR-swizzled at 16B granules.
// EPI 0: store bf16.  1: +bias, ReLU, bf16.  2: +bias +resid, f32.
template <int WTN, int EPI>
__device__ __forceinline__ void gemm_core(const u16* __restrict__ A,
                                          const u16* __restrict__ Bt,
                                          u16* __restrict__ outb,
                                          float* __restrict__ outf,
                                          const float* __restrict__ bias,
                                          const float* __restrict__ resid,
                                          int N, int K, int m0, int n0) {
  constexpr int BM = 128, BN = 2 * WTN;
  constexpr int NI = WTN / 16;          // 4 or 2
  constexpr int BCH = BN / 8;           // B chunks
  constexpr int LPW = (16 + BCH) / 4;   // gll16 per wave per stage (8 or 6)
  __shared__ alignas(16) u16 sA[2][BM * 64];
  __shared__ alignas(16) u16 sB[2][BN * 64];
  const int tid = threadIdx.x, lane = tid & 63, wid = tid >> 6;
  const int wm = (wid >> 1) * 64, wn = (wid & 1) * WTN;
  const int lr = lane & 15, lg = lane >> 4;
  const int srow = lane >> 3;                 // row within 8-row chunk
  const int sgr = (lane & 7) ^ srow;          // pre-swizzled source granule
  const int x7 = lr & 7;                      // read-side swizzle key
  f32x4 acc[4][NI] = {};

  auto stage = [&](int buf, int k0) {
#pragma unroll
    for (int i = 0; i < LPW; ++i) {
      const int c = wid * LPW + i;
      if (c < 16) {
        const int r = c * 8 + srow;
        gll16(A + (size_t)(m0 + r) * K + k0 + sgr * 8, &sA[buf][c * 512]);
      } else {
        const int r = (c - 16) * 8 + srow;
        gll16(Bt + (size_t)(n0 + r) * K + k0 + sgr * 8, &sB[buf][(c - 16) * 512]);
      }
    }
  };

  const int nsteps = K >> 6;
  stage(0, 0);
  int cur = 0;
  for (int t = 0; t < nsteps; ++t) {
    if (t + 1 < nsteps) {
      stage(cur ^ 1, (t + 1) * 64);  // prefetch stays in flight across barriers
      wait_vm<LPW>();                // tile t's loads (oldest) have landed
    } else {
      wait_vm<0>();
    }
    barrier_raw();
    bf16x8 af[4][2], bfr[NI][2];
#pragma unroll
    for (int mi = 0; mi < 4; ++mi)
#pragma unroll
      for (int kk = 0; kk < 2; ++kk)
        af[mi][kk] = ldbf8(&sA[cur][(wm + mi * 16 + lr) * 64 + (((kk * 4 + lg) ^ x7) * 8)]);
#pragma unroll
    for (int ni = 0; ni < NI; ++ni)
#pragma unroll
      for (int kk = 0; kk < 2; ++kk)
        bfr[ni][kk] = ldbf8(&sB[cur][(wn + ni * 16 + lr) * 64 + (((kk * 4 + lg) ^ x7) * 8)]);
#pragma unroll
    for (int kk = 0; kk < 2; ++kk)
#pragma unroll
      for (int mi = 0; mi < 4; ++mi)
#pragma unroll
        for (int ni = 0; ni < NI; ++ni)
          acc[mi][ni] = MFMA16(af[mi][kk], bfr[ni][kk], acc[mi][ni], 0, 0, 0);
    barrier_raw();                   // WAR: reads done before next overwrite
    cur ^= 1;
  }

#pragma unroll
  for (int mi = 0; mi < 4; ++mi)
#pragma unroll
    for (int ni = 0; ni < NI; ++ni)
#pragma unroll
      for (int r = 0; r < 4; ++r) {
        const int row = m0 + wm + mi * 16 + lg * 4 + r;   // C/D: row=(lane>>4)*4+reg
        const int col = n0 + wn + ni * 16 + lr;           //      col=lane&15
        float v = acc[mi][ni][r];
        if (EPI == 0) {
          outb[(size_t)row * N + col] = f2bf(v);
        } else if (EPI == 1) {
          v += bias[col];
          v = fmaxf(v, 0.f);
          outb[(size_t)row * N + col] = f2bf(v);
        } else {
          v += bias[col] + resid[(size_t)row * N + col];
          outf[(size_t)row * N + col] = v;
        }
      }
}

// standalone GEMM (MLP1/MLP2) with XCD swizzle
template <int WTN, int EPI, int MINW>
__global__ __launch_bounds__(256, MINW) void gemm_kernel(const u16* __restrict__ A,
                                                         const u16* __restrict__ Bt,
                                                         u16* __restrict__ outb,
                                                         float* __restrict__ outf,
                                                         const float* __restrict__ bias,
                                                         const float* __restrict__ resid,
                                                         int N, int K) {
  constexpr int BN = 2 * WTN;
  const int gx = gridDim.x;
  const int nwg = gx * gridDim.y;
  int bid = blockIdx.y * gx + blockIdx.x;
  bid = (bid & 7) * (nwg >> 3) + (bid >> 3);
  const int n0 = (bid % gx) * BN, m0 = (bid / gx) * 128;
  gemm_core<WTN, EPI>(A, Bt, outb, outf, bias, resid, N, K, m0, n0);
}

// fused QK + V^T GEMM: blocks [0,512) -> QK (M=4096,N=2048); [512,768) -> VT
// (M=1024,N=4096). Both BN=128, K=1024. XCD swizzle within each segment.
__global__ __launch_bounds__(256, 2) void gemm_qkvt(const u16* __restrict__ hbuf,
                                                    const u16* __restrict__ wqkvt,
                                                    u16* __restrict__ qkb,
                                                    u16* __restrict__ vtb) {
  int bid = blockIdx.x;
  const u16 *A, *Bt;
  u16* outb;
  int N, m0, n0;
  if (bid < 512) {
    bid = (bid & 7) * 64 + (bid >> 3);
    A = hbuf; Bt = wqkvt; outb = qkb; N = 2048;
    n0 = (bid % 16) * 128; m0 = (bid / 16) * 128;
  } else {
    int b2 = bid - 512;
    b2 = (b2 & 7) * 32 + (b2 >> 3);
    A = wqkvt + 2048 * 1024; Bt = hbuf; outb = vtb; N = 4096;
    n0 = (b2 % 32) * 128; m0 = (b2 / 32) * 128;
  }
  gemm_core<64, 0>(A, Bt, outb, nullptr, nullptr, nullptr, N, 1024, m0, n0);
}

// ---------------- causal flash attention: split-s partial pass (r10) -------
// Single-buffered K/V (24 KB LDS -> 6 blocks/CU; TLP hides load latency).
// qk: bf16 [4096 tok][2048] (Q|K per head), Q pre-scaled to exp2 domain.
// vt: bf16 [1024 hd][4096 tok].
__global__ __launch_bounds__(256) void attn_partial(const u16* __restrict__ qk,
                                                    const u16* __restrict__ vt,
                                                    u16* __restrict__ Opart,
                                                    float2* __restrict__ ml) {
  const int xr = 79 - (int)blockIdx.x;  // heavy (long-range) blocks first
  int qb, ch, nc;
  if (xr < 8)       { qb = xr;                ch = 0;            nc = 1; }
  else if (xr < 24) { qb = 8 + ((xr - 8) >> 1);  ch = (xr - 8) & 1;  nc = 2; }
  else if (xr < 48) { qb = 16 + (xr - 24) / 3;   ch = (xr - 24) % 3; nc = 3; }
  else              { qb = 24 + ((xr - 48) >> 2); ch = (xr - 48) & 3; nc = 4; }
  const int nt_tot = qb + 1;
  const int t0 = (ch * nt_tot) / nc;
  const int t1 = ((ch + 1) * nt_tot) / nc;
  const int bh = blockIdx.y, b = bh >> 4, h = bh & 15;
  const int slot = bh * 80 + xr;
  const int q0 = qb * 64;
  const int tid = threadIdx.x, lane = tid & 63, w = tid >> 6;
  const int lr = lane & 15, lg = lane >> 4;
  __shared__ alignas(16) u16 sK[64 * 64];      // [s][d], 16B-granule XOR swizzle
  __shared__ alignas(16) u16 sV[64 * 64];      // [d][s], same swizzle
  __shared__ alignas(16) u16 sP[4][16 * 64];   // per-wave P, XOR-swizzled

  const size_t qrow = (size_t)(b * 2048 + q0 + w * 16 + lr) * 2048 + h * 64;
  const bf16x8 aq0 = ldbf8(qk + qrow + lg * 8);
  const bf16x8 aq1 = ldbf8(qk + qrow + 32 + lg * 8);

  float m_i[4], l_i[4];   // l_i: PER-LANE partial sums (reduced in epilogue)
  f32x4 acc[4];
#pragma unroll
  for (int r = 0; r < 4; ++r) { m_i[r] = -1e30f; l_i[r] = 0.f; }
#pragma unroll
  for (int dn = 0; dn < 4; ++dn) acc[dn] = f32x4{0.f, 0.f, 0.f, 0.f};

  auto stage = [&](int s0) {
#pragma unroll
    for (int i = 0; i < 2; ++i) {
      const int c = w * 2 + i;
      const int g = c * 64 + lane;
      const int row = g >> 3;
      const int cs = (g & 7) ^ (row & 7);
      gll16(qk + (size_t)(b * 2048 + s0 + row) * 2048 + 1024 + h * 64 + cs * 8,
            &sK[c * 512]);
      gll16(vt + (size_t)(h * 64 + row) * 4096 + b * 2048 + s0 + cs * 8,
            &sV[c * 512]);
    }
  };

  for (int t = t0; t < t1; ++t) {
    stage(t * 64);
    wait_vm<0>();
    barrier_raw();   // tile visible to all waves

    f32x4 sf[4];
    __builtin_amdgcn_s_setprio(1);
#pragma unroll
    for (int sn = 0; sn < 4; ++sn) {  // S[16q x 64s] = Q . K^T (exp2 domain)
      const int row = sn * 16 + lr;
      const int x7 = lr & 7;
      bf16x8 k0f = ldbf8(&sK[row * 64 + ((lg ^ x7) * 8)]);
      bf16x8 k1f = ldbf8(&sK[row * 64 + (((4 + lg) ^ x7) * 8)]);
      f32x4 z = {0.f, 0.f, 0.f, 0.f};
      z = MFMA16(aq0, k0f, z, 0, 0, 0);
      z = MFMA16(aq1, k1f, z, 0, 0, 0);
      sf[sn] = z;
    }
    __builtin_amdgcn_s_setprio(0);

    if (t == nt_tot - 1) {  // causal mask (last tile only)
      const int qlb = w * 16 + lg * 4;
#pragma unroll
      for (int sn = 0; sn < 4; ++sn)
#pragma unroll
        for (int r = 0; r < 4; ++r)
          if (sn * 16 + lr > qlb + r) sf[sn][r] = -1e30f;
    }

    // defer-max fast path: full reduce+rescale only when growth > 8
    float pm[4];
    bool need = false;
#pragma unroll
    for (int r = 0; r < 4; ++r) {
      pm[r] = fmaxf(fmaxf(sf[0][r], sf[1][r]), fmaxf(sf[2][r], sf[3][r]));
      need = need || (pm[r] > m_i[r] + 8.f);
    }
    if (__any(need)) {
#pragma unroll
      for (int r = 0; r < 4; ++r) {
        float mx = pm[r];
        mx = fmaxf(mx, __shfl_xor(mx, 1, 16));
        mx = fmaxf(mx, __shfl_xor(mx, 2, 16));
        mx = fmaxf(mx, __shfl_xor(mx, 4, 16));
        mx = fmaxf(mx, __shfl_xor(mx, 8, 16));
        const float mnew = fmaxf(m_i[r], mx);
        const float al = exp2f(m_i[r] - mnew);
        l_i[r] *= al;
        acc[0][r] *= al; acc[1][r] *= al; acc[2][r] *= al; acc[3][r] *= al;
        m_i[r] = mnew;
      }
    }

    // P = exp2(S - m); per-lane l accumulation; swizzled P store
    const int x7p = lr & 7;
#pragma unroll
    for (int r = 0; r < 4; ++r) {
      const float p0 = exp2f(sf[0][r] - m_i[r]), p1 = exp2f(sf[1][r] - m_i[r]);
      const float p2 = exp2f(sf[2][r] - m_i[r]), p3 = exp2f(sf[3][r] - m_i[r]);
      l_i[r] += (p0 + p1) + (p2 + p3);
      const int prow = lg * 4 + r;
      const int pb = prow * 64, px = prow & 7;
      sP[w][pb + (((lr >> 3) ^ px) * 8) + (lr & 7)]       = f2bf(p0);
      sP[w][pb + (((2 + (lr >> 3)) ^ px) * 8) + (lr & 7)] = f2bf(p1);
      sP[w][pb + (((4 + (lr >> 3)) ^ px) * 8) + (lr & 7)] = f2bf(p2);
      sP[w][pb + (((6 + (lr >> 3)) ^ px) * 8) + (lr & 7)] = f2bf(p3);
    }

    // O += P . V   (wave-local P; compiler inserts lgkmcnt for the RAW)
    const bf16x8 pa0 = ldbf8(&sP[w][lr * 64 + ((lg ^ x7p) * 8)]);
    const bf16x8 pa1 = ldbf8(&sP[w][lr * 64 + (((4 + lg) ^ x7p) * 8)]);
    __builtin_amdgcn_s_setprio(1);
#pragma unroll
    for (int dn = 0; dn < 4; ++dn) {
      const int row = dn * 16 + lr;
      bf16x8 v0f = ldbf8(&sV[row * 64 + ((lg ^ x7p) * 8)]);
      bf16x8 v1f = ldbf8(&sV[row * 64 + (((4 + lg) ^ x7p) * 8)]);
      acc[dn] = MFMA16(pa0, v0f, acc[dn], 0, 0, 0);
      acc[dn] = MFMA16(pa1, v1f, acc[dn], 0, 0, 0);
    }
    __builtin_amdgcn_s_setprio(0);
    barrier_raw();  // WAR guard before next stage overwrites
  }

  // partial epilogue: reduce per-lane l, write unnormalized O (bf16) + (m,l)
  const int rbase = w * 16 + lg * 4;
#pragma unroll
  for (int r = 0; r < 4; ++r) {
    float ls = l_i[r];
    ls += __shfl_xor(ls, 1, 16);
    ls += __shfl_xor(ls, 2, 16);
    ls += __shfl_xor(ls, 4, 16);
    ls += __shfl_xor(ls, 8, 16);
    const int row = rbase + r;
    if (lr == 0) ml[(size_t)slot * 64 + row] = make_float2(m_i[r], ls);
#pragma unroll
    for (int dn = 0; dn < 4; ++dn)
      Opart[((size_t)slot * 64 + row) * 64 + dn * 16 + lr] = f2bf(acc[dn][r]);
  }
}

// ---------------- attention merge + residual + LN2 partial sums ------------
__global__ __launch_bounds__(256) void attn_merge_ln(const u16* __restrict__ Opart,
                                                     const float2* __restrict__ ml,
                                                     const float* __restrict__ x,
                                                     float* __restrict__ x2,
                                                     float2* __restrict__ part) {
  const int qb = blockIdx.x, bh = blockIdx.y, b = bh >> 4, h = bh & 15;
  const int nc = (qb >> 3) + 1;
  const size_t slot0 = (size_t)bh * 80 + qb_off(qb);
  const int tid = threadIdx.x;
  const int row = tid >> 2, d0 = (tid & 3) * 16;
  __shared__ float red[64][65];

  float wgt[4];
  float mmax = -1e30f, lsum = 0.f;
  for (int i = 0; i < nc; ++i) {
    float2 v = ml[(slot0 + i) * 64 + row];
    wgt[i] = v.x;
    mmax = fmaxf(mmax, v.x);
  }
  for (int i = 0; i < nc; ++i) {
    float2 v = ml[(slot0 + i) * 64 + row];
    wgt[i] = exp2f(wgt[i] - mmax);
    lsum += wgt[i] * v.y;
  }
  const float inv = 1.0f / lsum;

#pragma unroll
  for (int half = 0; half < 2; ++half) {
    const int d = d0 + half * 8;
    float o[8] = {0.f, 0.f, 0.f, 0.f, 0.f, 0.f, 0.f, 0.f};
    for (int i = 0; i < nc; ++i) {
      u16x8 v = *reinterpret_cast<const u16x8*>(&Opart[((slot0 + i) * 64 + row) * 64 + d]);
#pragma unroll
      for (int jj = 0; jj < 8; ++jj) o[jj] += wgt[i] * bf2f(v[jj]);
    }
    const size_t idx = ((size_t)(b * 2048 + qb * 64 + row)) * 1024 + h * 64 + d;
    float4 x0 = *reinterpret_cast<const float4*>(x + idx);
    float4 x1 = *reinterpret_cast<const float4*>(x + idx + 4);
    float4 o0 = make_float4(x0.x + o[0] * inv, x0.y + o[1] * inv, x0.z + o[2] * inv, x0.w + o[3] * inv);
    float4 o1 = make_float4(x1.x + o[4] * inv, x1.y + o[5] * inv, x1.z + o[6] * inv, x1.w + o[7] * inv);
    *reinterpret_cast<float4*>(x2 + idx) = o0;
    *reinterpret_cast<float4*>(x2 + idx + 4) = o1;
    red[row][d + 0] = o0.x; red[row][d + 1] = o0.y; red[row][d + 2] = o0.z; red[row][d + 3] = o0.w;
    red[row][d + 4] = o1.x; red[row][d + 5] = o1.y; red[row][d + 6] = o1.z; red[row][d + 7] = o1.w;
  }
  __syncthreads();
  if (tid < 64) {  // column-reduce over the 64 t-rows
    float s = 0.f, sq = 0.f;
#pragma unroll 8
    for (int t = 0; t < 64; ++t) {
      float v = red[t][tid];
      s += v; sq += v * v;
    }
    part[(size_t)(b * 1024 + h * 64 + tid) * 32 + qb] = make_float2(s, sq);
  }
}

// ---------------------------------------------------------------------------
extern "C" void kernel_launch(void* const* d_in, const int* in_sizes, int n_in,
                              void* d_out, int out_size, void* d_ws, size_t ws_size,
                              hipStream_t stream) {
  const float* x   = (const float*)d_in[0];
  const float* Wq  = (const float*)d_in[1];
  const float* Wk  = (const float*)d_in[2];
  const float* Wv  = (const float*)d_in[3];
  const float* W1  = (const float*)d_in[4];
  const float* b1  = (const float*)d_in[5];
  const float* W2  = (const float*)d_in[6];
  const float* b2  = (const float*)d_in[7];
  const float* g1  = (const float*)d_in[8];
  const float* be1 = (const float*)d_in[9];
  const float* g2  = (const float*)d_in[10];
  const float* be2 = (const float*)d_in[11];
  float* out = (float*)d_out;

  char* ws = (char*)d_ws;
  size_t off = 0;
  auto alloc = [&](size_t bytes) { char* p = ws + off; off += (bytes + 255) & ~(size_t)255; return p; };
  u16*    qkb   = (u16*)alloc(4096ull * 2048 * 2);   // [tok][Q|K]          16MB
  u16*    vtb   = (u16*)alloc(1024ull * 4096 * 2);   // [hd][tok]            8MB
  (void)alloc(4096ull * 1024 * 2);                   // h1 overflow region   8MB
  u16*    h1    = qkb;                               // MLP1 out aliases qk+vt+overflow (32MB)
  float*  x2    = (float*)alloc(4096ull * 1024 * 4); // x + attn            16MB
  u16*    hbuf  = (u16*)alloc(4096ull * 1024 * 2);   // LN outputs           8MB
  u16*    wqkvt = (u16*)alloc(3072ull * 1024 * 2);
  u16*    w1t   = (u16*)alloc(4096ull * 1024 * 2);
  u16*    w2t   = (u16*)alloc(1024ull * 4096 * 2);
  float2* part  = (float2*)alloc(2048ull * 32 * 8);  // LN partials (8 or 32 chunks)
  float2* stats = (float2*)alloc(2048ull * 8);       // (unused, kept for layout)
  u16*    Opart = (u16*)alloc(32ull * 80 * 64 * 64 * 2);   // ~21MB
  float2* ml    = (float2*)alloc(32ull * 80 * 64 * 8);     // ~1.3MB
  (void)ws_size; (void)in_sizes; (void)n_in; (void)out_size; (void)stats;

  // fused prep: weight transposes (Wq scaled by C^-0.5*log2e) + LN1 partials
  const float SC = 0.03125f * 1.44269504088896341f;
  prep_fused<<<3072, 256, 0, stream>>>(Wq, Wk, Wv, W1, W2, x, wqkvt, w1t, w2t, part, SC);

  // LN1: fused stats+apply -> hbuf (bf16)
  ln_stats_apply<8><<<dim3(16, 8, 2), 256, 0, stream>>>(x, part, g1, be1, hbuf);

  // fused QK GEMM (-> qkb [4096][2048]) + V^T GEMM (-> vtb [1024][4096])
  gemm_qkvt<<<768, 256, 0, stream>>>(hbuf, wqkvt, qkb, vtb);

  // attention: split-s partials (r10), then merge + residual + LN2 partials
  attn_partial<<<dim3(80, 32), 256, 0, stream>>>(qkb, vtb, Opart, ml);
  attn_merge_ln<<<dim3(32, 32), 256, 0, stream>>>(Opart, ml, x, x2, part);

  // LN2: fused stats+apply -> hbuf (bf16)
  ln_stats_apply<32><<<dim3(16, 8, 2), 256, 0, stream>>>(x2, part, g2, be2, hbuf);

  // MLP1: relu(h @ W1 + b1) -> h1 (bf16 [4096][4096])   (BN=128)
  gemm_kernel<64, 1, 2><<<dim3(32, 32), 256, 0, stream>>>(hbuf, w1t, h1, nullptr, b1, nullptr, 4096, 1024);

  // MLP2: x2 + h1 @ W2 + b2 -> out (f32)   (BN=64)
  gemm_kernel<32, 2, 3><<<dim3(16, 32), 256, 0, stream>>>(h1, w2t, nullptr, out, b2, x2, 1024, 4096);
}

// Round 19
// 218.429 us; speedup vs baseline: 1.1511x; 1.0229x over previous
//
#include <hip/hip_runtime.h>

// ---------------------------------------------------------------------------
// Transformer block on MI355X (gfx950), bf16 MFMA pipeline, fp32 residual/LN.
//   x:[2,2048,1024]  LN over T (ddof=1) -> fused QK+V^T GEMM -> causal flash
//   attn (r10 structure; nc==1 blocks finalize in-place) + merge (qb>=8)
//   -> fused LN stats+apply -> MLP -> +resid
// r19: r17's nc==1 fusion retried WITHOUT the launch_bounds pin that caused
//      the VGPR-40 spill regression. Everything else identical to r18/r14.
// ---------------------------------------------------------------------------

typedef __bf16 bf16x8 __attribute__((ext_vector_type(8)));
typedef float f32x4 __attribute__((ext_vector_type(4)));
typedef unsigned short u16;
typedef u16 u16x8 __attribute__((ext_vector_type(8)));
typedef u16 u16x4 __attribute__((ext_vector_type(4)));

#define MFMA16 __builtin_amdgcn_mfma_f32_16x16x32_bf16

__device__ __forceinline__ u16 f2bf(float f) {  // native v_cvt (RNE)
  return __builtin_bit_cast(u16, (__bf16)f);
}
__device__ __forceinline__ float bf2f(u16 u) {
  return __builtin_bit_cast(float, (unsigned)u << 16);
}
__device__ __forceinline__ bf16x8 ldbf8(const u16* p) {
  return __builtin_bit_cast(bf16x8, *reinterpret_cast<const u16x8*>(p));
}
// async global->LDS, 16B per lane, dest = wave-uniform base + lane*16
__device__ __forceinline__ void gll16(const void* g, void* l) {
  __builtin_amdgcn_global_load_lds((const __attribute__((address_space(1))) void*)g,
                                   (__attribute__((address_space(3))) void*)l, 16, 0, 0);
}
template <int N>
__device__ __forceinline__ void wait_vm() {
  if constexpr (N == 0)      asm volatile("s_waitcnt vmcnt(0)" ::: "memory");
  else if constexpr (N == 6) asm volatile("s_waitcnt vmcnt(6)" ::: "memory");
  else if constexpr (N == 8) asm volatile("s_waitcnt vmcnt(8)" ::: "memory");
  else                       asm volatile("s_waitcnt vmcnt(16)" ::: "memory");
}
__device__ __forceinline__ void barrier_raw() {
  asm volatile("" ::: "memory");
  __builtin_amdgcn_s_barrier();
  asm volatile("" ::: "memory");
}
// slot offset table for (qb, chunk): 80 slots per bh
__device__ __forceinline__ int qb_off(int qb) {
  if (qb < 8)  return qb;
  if (qb < 16) return 8 + (qb - 8) * 2;
  if (qb < 24) return 24 + (qb - 16) * 3;
  return 48 + (qb - 24) * 4;
}

// ---------------- fused prep: weight transposes + LN1 partials -------------
// blocks [0,768): Wq/Wk/Wv -> wqkvt (Wq scaled).  [768,2816): W1/W2 -> w1t/w2t.
// [2816,3072): LN1 partial sums of x.
__global__ __launch_bounds__(256) void prep_fused(const float* __restrict__ Wq,
                                                  const float* __restrict__ Wk,
                                                  const float* __restrict__ Wv,
                                                  const float* __restrict__ W1,
                                                  const float* __restrict__ W2,
                                                  const float* __restrict__ x,
                                                  u16* __restrict__ wqkvt,
                                                  u16* __restrict__ w1t,
                                                  u16* __restrict__ w2t,
                                                  float2* __restrict__ part,
                                                  float scale) {
  __shared__ alignas(16) char smem[64 * 65 * 4];
  const int id = blockIdx.x;
  if (id < 2816) {  // a 64x64 f32->bf16 transpose tile
    const float* in;
    u16* out;
    int K, N, kb, nb, roff = 0;
    float sc = 1.0f;
    if (id < 768) {
      const int z = id >> 8, rem = id & 255;
      in = z == 0 ? Wq : (z == 1 ? Wk : Wv);
      if (z == 0) sc = scale;
      out = wqkvt;
      K = 1024; N = 64;
      kb = rem & 15; nb = 0;
      roff = z * 1024 + (rem >> 4) * 64;   // head row offset
      in += (size_t)(rem >> 4) * 1024 * 64;
    } else if (id < 1792) {
      const int i2 = id - 768;
      in = W1; out = w1t; K = 1024; N = 4096; kb = i2 & 15; nb = i2 >> 4;
    } else {
      const int i2 = id - 1792;
      in = W2; out = w2t; K = 4096; N = 1024; kb = i2 >> 4; nb = i2 & 15;
    }
    float (*tile)[65] = (float(*)[65])smem;
    const int k0 = kb * 64, n0 = nb * 64;
    const int c = threadIdx.x & 63, rg = threadIdx.x >> 6;
#pragma unroll
    for (int i = 0; i < 16; ++i) {
      int r = rg * 16 + i;
      tile[r][c] = in[(size_t)(k0 + r) * N + n0 + c];
    }
    __syncthreads();
#pragma unroll
    for (int i = 0; i < 16; ++i) {
      int nl = rg * 16 + i;
      out[(size_t)(roff + n0 + nl) * K + k0 + c] = f2bf(tile[c][nl] * sc);
    }
  } else {  // LN1 partial sums
    const int idm = id - 2816;
    const int bx = idm & 31, by = idm >> 5;
    const int b = bx >> 4, c0 = (bx & 15) * 64;
    const int c = c0 + (threadIdx.x & 63), tg = threadIdx.x >> 6;
    const int t0 = by * 256 + tg * 64;
    float s = 0.f, sq = 0.f;
    const float* p = x + (size_t)(b * 2048 + t0) * 1024 + c;
#pragma unroll 8
    for (int i = 0; i < 64; ++i) {
      float v = p[(size_t)i * 1024];
      s += v; sq += v * v;
    }
    float* ss = (float*)smem;
    float* sb = ss + 256;
    ss[threadIdx.x] = s; sb[threadIdx.x] = sq;
    __syncthreads();
    if (threadIdx.x < 64) {
      s  = ss[threadIdx.x] + ss[threadIdx.x + 64] + ss[threadIdx.x + 128] + ss[threadIdx.x + 192];
      sq = sb[threadIdx.x] + sb[threadIdx.x + 64] + sb[threadIdx.x + 128] + sb[threadIdx.x + 192];
      part[(size_t)(b * 1024 + c) * 8 + by] = make_float2(s, sq);
    }
  }
}

// ---------------- fused LayerNorm stats + apply ----------------------------
template <int NC>
__global__ __launch_bounds__(256) void ln_stats_apply(const float* __restrict__ x,
                                                      const float2* __restrict__ part,
                                                      const float* __restrict__ g,
                                                      const float* __restrict__ be,
                                                      u16* __restrict__ out) {
  const int slab = blockIdx.x * 64;
  const int y0 = blockIdx.y * 256;
  const int b = blockIdx.z;
  const int tid = threadIdx.x;
  __shared__ float2 sst[64];
  __shared__ float sg[64], sbe[64];
  if (tid < 64) {
    const int c = slab + tid;
    float s = 0.f, sq = 0.f;
#pragma unroll
    for (int i = 0; i < NC; ++i) {
      float2 v = part[(size_t)(b * 1024 + c) * NC + i];
      s += v.x; sq += v.y;
    }
    const float mean = s * (1.0f / 2048.0f);
    const float var = (sq - 2048.0f * mean * mean) * (1.0f / 2047.0f);  // ddof=1
    sst[tid] = make_float2(mean, rsqrtf(var + 1e-5f));
    sg[tid] = g[c];
    sbe[tid] = be[c];
  }
  __syncthreads();
  const int c4 = (tid & 15) * 4;   // col within slab
  const int r0 = tid >> 4;         // row group 0..15
  const size_t base = ((size_t)(b * 2048 + y0)) * 1024 + slab + c4;
#pragma unroll
  for (int it = 0; it < 16; ++it) {
    const int row = r0 * 16 + it;
    float4 xv = *reinterpret_cast<const float4*>(x + base + (size_t)row * 1024);
    float vs[4] = {xv.x, xv.y, xv.z, xv.w};
    u16x4 o;
#pragma unroll
    for (int j = 0; j < 4; ++j) {
      float2 st = sst[c4 + j];
      o[j] = f2bf(sg[c4 + j] * (vs[j] - st.x) * st.y + sbe[c4 + j]);
    }
    *reinterpret_cast<u16x4*>(out + base + (size_t)row * 1024) = o;
  }
}

// ---------------- GEMM core: C = A[M,K] x Bt[N,K]^T ------------------------
// 256 threads / 4 waves (2x2), wave tile 64 x WTN. BM=128, BN=2*WTN, BK=64.
// Double-buffered, counted vmcnt. LDS XOR-swizzled at 16B granules.
// EPI 0: store bf16.  1: +bias, ReLU, bf16.  2: +bias +resid, f32.
template <int WTN, int EPI>
__device__ __forceinline__ void gemm_core(const u16* __restrict__ A,
                                          const u16* __restrict__ Bt,
                                          u16* __restrict__ outb,
                                          float* __restrict__ outf,
                                          const float* __restrict__ bias,
                                          const float* __restrict__ resid,
                                          int N, int K, int m0, int n0) {
  constexpr int BM = 128, BN = 2 * WTN;
  constexpr int NI = WTN / 16;          // 4 or 2
  constexpr int BCH = BN / 8;           // B chunks
  constexpr int LPW = (16 + BCH) / 4;   // gll16 per wave per stage (8 or 6)
  __shared__ alignas(16) u16 sA[2][BM * 64];
  __shared__ alignas(16) u16 sB[2][BN * 64];
  const int tid = threadIdx.x, lane = tid & 63, wid = tid >> 6;
  const int wm = (wid >> 1) * 64, wn = (wid & 1) * WTN;
  const int lr = lane & 15, lg = lane >> 4;
  const int srow = lane >> 3;                 // row within 8-row chunk
  const int sgr = (lane & 7) ^ srow;          // pre-swizzled source granule
  const int x7 = lr & 7;                      // read-side swizzle key
  f32x4 acc[4][NI] = {};

  auto stage = [&](int buf, int k0) {
#pragma unroll
    for (int i = 0; i < LPW; ++i) {
      const int c = wid * LPW + i;
      if (c < 16) {
        const int r = c * 8 + srow;
        gll16(A + (size_t)(m0 + r) * K + k0 + sgr * 8, &sA[buf][c * 512]);
      } else {
        const int r = (c - 16) * 8 + srow;
        gll16(Bt + (size_t)(n0 + r) * K + k0 + sgr * 8, &sB[buf][(c - 16) * 512]);
      }
    }
  };

  const int nsteps = K >> 6;
  stage(0, 0);
  int cur = 0;
  for (int t = 0; t < nsteps; ++t) {
    if (t + 1 < nsteps) {
      stage(cur ^ 1, (t + 1) * 64);  // prefetch stays in flight across barriers
      wait_vm<LPW>();                // tile t's loads (oldest) have landed
    } else {
      wait_vm<0>();
    }
    barrier_raw();
    bf16x8 af[4][2], bfr[NI][2];
#pragma unroll
    for (int mi = 0; mi < 4; ++mi)
#pragma unroll
      for (int kk = 0; kk < 2; ++kk)
        af[mi][kk] = ldbf8(&sA[cur][(wm + mi * 16 + lr) * 64 + (((kk * 4 + lg) ^ x7) * 8)]);
#pragma unroll
    for (int ni = 0; ni < NI; ++ni)
#pragma unroll
      for (int kk = 0; kk < 2; ++kk)
        bfr[ni][kk] = ldbf8(&sB[cur][(wn + ni * 16 + lr) * 64 + (((kk * 4 + lg) ^ x7) * 8)]);
#pragma unroll
    for (int kk = 0; kk < 2; ++kk)
#pragma unroll
      for (int mi = 0; mi < 4; ++mi)
#pragma unroll
        for (int ni = 0; ni < NI; ++ni)
          acc[mi][ni] = MFMA16(af[mi][kk], bfr[ni][kk], acc[mi][ni], 0, 0, 0);
    barrier_raw();                   // WAR: reads done before next overwrite
    cur ^= 1;
  }

#pragma unroll
  for (int mi = 0; mi < 4; ++mi)
#pragma unroll
    for (int ni = 0; ni < NI; ++ni)
#pragma unroll
      for (int r = 0; r < 4; ++r) {
        const int row = m0 + wm + mi * 16 + lg * 4 + r;   // C/D: row=(lane>>4)*4+reg
        const int col = n0 + wn + ni * 16 + lr;           //      col=lane&15
        float v = acc[mi][ni][r];
        if (EPI == 0) {
          outb[(size_t)row * N + col] = f2bf(v);
        } else if (EPI == 1) {
          v += bias[col];
          v = fmaxf(v, 0.f);
          outb[(size_t)row * N + col] = f2bf(v);
        } else {
          v += bias[col] + resid[(size_t)row * N + col];
          outf[(size_t)row * N + col] = v;
        }
      }
}

// standalone GEMM (MLP1/MLP2) with XCD swizzle
template <int WTN, int EPI, int MINW>
__global__ __launch_bounds__(256, MINW) void gemm_kernel(const u16* __restrict__ A,
                                                         const u16* __restrict__ Bt,
                                                         u16* __restrict__ outb,
                                                         float* __restrict__ outf,
                                                         const float* __restrict__ bias,
                                                         const float* __restrict__ resid,
                                                         int N, int K) {
  constexpr int BN = 2 * WTN;
  const int gx = gridDim.x;
  const int nwg = gx * gridDim.y;
  int bid = blockIdx.y * gx + blockIdx.x;
  bid = (bid & 7) * (nwg >> 3) + (bid >> 3);
  const int n0 = (bid % gx) * BN, m0 = (bid / gx) * 128;
  gemm_core<WTN, EPI>(A, Bt, outb, outf, bias, resid, N, K, m0, n0);
}

// fused QK + V^T GEMM: blocks [0,512) -> QK (M=4096,N=2048); [512,768) -> VT
// (M=1024,N=4096). Both BN=128, K=1024. XCD swizzle within each segment.
__global__ __launch_bounds__(256, 2) void gemm_qkvt(const u16* __restrict__ hbuf,
                                                    const u16* __restrict__ wqkvt,
                                                    u16* __restrict__ qkb,
                                                    u16* __restrict__ vtb) {
  int bid = blockIdx.x;
  const u16 *A, *Bt;
  u16* outb;
  int N, m0, n0;
  if (bid < 512) {
    bid = (bid & 7) * 64 + (bid >> 3);
    A = hbuf; Bt = wqkvt; outb = qkb; N = 2048;
    n0 = (bid % 16) * 128; m0 = (bid / 16) * 128;
  } else {
    int b2 = bid - 512;
    b2 = (b2 & 7) * 32 + (b2 >> 3);
    A = wqkvt + 2048 * 1024; Bt = hbuf; outb = vtb; N = 4096;
    n0 = (b2 % 32) * 128; m0 = (b2 / 32) * 128;
  }
  gemm_core<64, 0>(A, Bt, outb, nullptr, nullptr, nullptr, N, 1024, m0, n0);
}

// ---------------- causal flash attention: split-s partial pass -------------
// r10 structure (NO launch-bounds pin — r17's VGPR-40 spill cause removed).
// nc==1 blocks (qb<8, full s-range) finalize in-place: normalize, +residual,
// write x2, LN2 column partials via dead-LDS float buffer.
// qk: bf16 [4096 tok][2048] (Q|K per head), Q pre-scaled to exp2 domain.
// vt: bf16 [1024 hd][4096 tok].
__global__ void attn_partial(const u16* __restrict__ qk,
                             const u16* __restrict__ vt,
                             const float* __restrict__ x,
                             float* __restrict__ x2,
                             u16* __restrict__ Opart,
                             float2* __restrict__ ml,
                             float2* __restrict__ part) {
  const int xr = 79 - (int)blockIdx.x;  // heavy (long-range) blocks first
  int qb, ch, nc;
  if (xr < 8)       { qb = xr;                ch = 0;            nc = 1; }
  else if (xr < 24) { qb = 8 + ((xr - 8) >> 1);  ch = (xr - 8) & 1;  nc = 2; }
  else if (xr < 48) { qb = 16 + (xr - 24) / 3;   ch = (xr - 24) % 3; nc = 3; }
  else              { qb = 24 + ((xr - 48) >> 2); ch = (xr - 48) & 3; nc = 4; }
  const int nt_tot = qb + 1;
  const int t0 = (ch * nt_tot) / nc;
  const int t1 = ((ch + 1) * nt_tot) / nc;
  const int bh = blockIdx.y, b = bh >> 4, h = bh & 15;
  const int slot = bh * 80 + xr;
  const int q0 = qb * 64;
  const int tid = threadIdx.x, lane = tid & 63, w = tid >> 6;
  const int lr = lane & 15, lg = lane >> 4;
  // 24 KB carved LDS: sK 8KB | sV 8KB | sP 8KB; float fbuf aliases all of it
  // in the nc==1 epilogue (safe: loop-ending barrier makes them dead).
  __shared__ alignas(16) char smem[24576];
  u16* const sK = (u16*)smem;
  u16* const sV = (u16*)(smem + 8192);
  u16* const sPw = (u16*)(smem + 16384) + w * (16 * 64);

  const size_t qrow = (size_t)(b * 2048 + q0 + w * 16 + lr) * 2048 + h * 64;
  const bf16x8 aq0 = ldbf8(qk + qrow + lg * 8);
  const bf16x8 aq1 = ldbf8(qk + qrow + 32 + lg * 8);

  float m_i[4], l_i[4];   // l_i: PER-LANE partial sums (reduced in epilogue)
  f32x4 acc[4];
#pragma unroll
  for (int r = 0; r < 4; ++r) { m_i[r] = -1e30f; l_i[r] = 0.f; }
#pragma unroll
  for (int dn = 0; dn < 4; ++dn) acc[dn] = f32x4{0.f, 0.f, 0.f, 0.f};

  auto stage = [&](int s0) {
#pragma unroll
    for (int i = 0; i < 2; ++i) {
      const int c = w * 2 + i;
      const int g = c * 64 + lane;
      const int row = g >> 3;
      const int cs = (g & 7) ^ (row & 7);
      gll16(qk + (size_t)(b * 2048 + s0 + row) * 2048 + 1024 + h * 64 + cs * 8,
            &sK[c * 512]);
      gll16(vt + (size_t)(h * 64 + row) * 4096 + b * 2048 + s0 + cs * 8,
            &sV[c * 512]);
    }
  };

  for (int t = t0; t < t1; ++t) {
    stage(t * 64);
    wait_vm<0>();
    barrier_raw();   // tile visible to all waves

    f32x4 sf[4];
    __builtin_amdgcn_s_setprio(1);
#pragma unroll
    for (int sn = 0; sn < 4; ++sn) {  // S[16q x 64s] = Q . K^T (exp2 domain)
      const int row = sn * 16 + lr;
      const int x7 = lr & 7;
      bf16x8 k0f = ldbf8(&sK[row * 64 + ((lg ^ x7) * 8)]);
      bf16x8 k1f = ldbf8(&sK[row * 64 + (((4 + lg) ^ x7) * 8)]);
      f32x4 z = {0.f, 0.f, 0.f, 0.f};
      z = MFMA16(aq0, k0f, z, 0, 0, 0);
      z = MFMA16(aq1, k1f, z, 0, 0, 0);
      sf[sn] = z;
    }
    __builtin_amdgcn_s_setprio(0);

    if (t == nt_tot - 1) {  // causal mask (last tile only)
      const int qlb = w * 16 + lg * 4;
#pragma unroll
      for (int sn = 0; sn < 4; ++sn)
#pragma unroll
        for (int r = 0; r < 4; ++r)
          if (sn * 16 + lr > qlb + r) sf[sn][r] = -1e30f;
    }

    // defer-max fast path: full reduce+rescale only when growth > 8
    float pm[4];
    bool need = false;
#pragma unroll
    for (int r = 0; r < 4; ++r) {
      pm[r] = fmaxf(fmaxf(sf[0][r], sf[1][r]), fmaxf(sf[2][r], sf[3][r]));
      need = need || (pm[r] > m_i[r] + 8.f);
    }
    if (__any(need)) {
#pragma unroll
      for (int r = 0; r < 4; ++r) {
        float mx = pm[r];
        mx = fmaxf(mx, __shfl_xor(mx, 1, 16));
        mx = fmaxf(mx, __shfl_xor(mx, 2, 16));
        mx = fmaxf(mx, __shfl_xor(mx, 4, 16));
        mx = fmaxf(mx, __shfl_xor(mx, 8, 16));
        const float mnew = fmaxf(m_i[r], mx);
        const float al = exp2f(m_i[r] - mnew);
        l_i[r] *= al;
        acc[0][r] *= al; acc[1][r] *= al; acc[2][r] *= al; acc[3][r] *= al;
        m_i[r] = mnew;
      }
    }

    // P = exp2(S - m); per-lane l accumulation; swizzled P store
    const int x7p = lr & 7;
#pragma unroll
    for (int r = 0; r < 4; ++r) {
      const float p0 = exp2f(sf[0][r] - m_i[r]), p1 = exp2f(sf[1][r] - m_i[r]);
      const float p2 = exp2f(sf[2][r] - m_i[r]), p3 = exp2f(sf[3][r] - m_i[r]);
      l_i[r] += (p0 + p1) + (p2 + p3);
      const int prow = lg * 4 + r;
      const int pb = prow * 64, px = prow & 7;
      sPw[pb + (((lr >> 3) ^ px) * 8) + (lr & 7)]       = f2bf(p0);
      sPw[pb + (((2 + (lr >> 3)) ^ px) * 8) + (lr & 7)] = f2bf(p1);
      sPw[pb + (((4 + (lr >> 3)) ^ px) * 8) + (lr & 7)] = f2bf(p2);
      sPw[pb + (((6 + (lr >> 3)) ^ px) * 8) + (lr & 7)] = f2bf(p3);
    }

    // O += P . V   (wave-local P; compiler inserts lgkmcnt for the RAW)
    const bf16x8 pa0 = ldbf8(&sPw[lr * 64 + ((lg ^ x7p) * 8)]);
    const bf16x8 pa1 = ldbf8(&sPw[lr * 64 + (((4 + lg) ^ x7p) * 8)]);
    __builtin_amdgcn_s_setprio(1);
#pragma unroll
    for (int dn = 0; dn < 4; ++dn) {
      const int row = dn * 16 + lr;
      bf16x8 v0f = ldbf8(&sV[row * 64 + ((lg ^ x7p) * 8)]);
      bf16x8 v1f = ldbf8(&sV[row * 64 + (((4 + lg) ^ x7p) * 8)]);
      acc[dn] = MFMA16(pa0, v0f, acc[dn], 0, 0, 0);
      acc[dn] = MFMA16(pa1, v1f, acc[dn], 0, 0, 0);
    }
    __builtin_amdgcn_s_setprio(0);
    barrier_raw();  // WAR guard before next stage overwrites
  }

  const int rbase = w * 16 + lg * 4;
  if (nc == 1) {
    // full s-range covered: finalize here (normalize, +resid, LN2 partials)
    float* fbuf = (float*)smem;   // 64x65 floats; sK/sV/sP dead (loop barrier)
#pragma unroll
    for (int r = 0; r < 4; ++r) {
      float ls = l_i[r];
      ls += __shfl_xor(ls, 1, 16);
      ls += __shfl_xor(ls, 2, 16);
      ls += __shfl_xor(ls, 4, 16);
      ls += __shfl_xor(ls, 8, 16);
      const float inv = 1.0f / ls;
      const int row = rbase + r;
#pragma unroll
      for (int dn = 0; dn < 4; ++dn) {
        const size_t idx = ((size_t)(b * 2048 + q0 + row)) * 1024 + h * 64 + dn * 16 + lr;
        const float val = x[idx] + acc[dn][r] * inv;
        x2[idx] = val;
        fbuf[row * 65 + dn * 16 + lr] = val;
      }
    }
    __syncthreads();
    if (tid < 64) {  // LN2 column partials over this block's 64 t-rows
      float s = 0.f, sq = 0.f;
#pragma unroll 8
      for (int t2 = 0; t2 < 64; ++t2) {
        float v = fbuf[t2 * 65 + tid];
        s += v; sq += v * v;
      }
      part[(size_t)(b * 1024 + h * 64 + tid) * 32 + qb] = make_float2(s, sq);
    }
  } else {
    // partial epilogue: reduce per-lane l, write unnormalized O (bf16) + (m,l)
#pragma unroll
    for (int r = 0; r < 4; ++r) {
      float ls = l_i[r];
      ls += __shfl_xor(ls, 1, 16);
      ls += __shfl_xor(ls, 2, 16);
      ls += __shfl_xor(ls, 4, 16);
      ls += __shfl_xor(ls, 8, 16);
      const int row = rbase + r;
      if (lr == 0) ml[(size_t)slot * 64 + row] = make_float2(m_i[r], ls);
#pragma unroll
      for (int dn = 0; dn < 4; ++dn)
        Opart[((size_t)slot * 64 + row) * 64 + dn * 16 + lr] = f2bf(acc[dn][r]);
    }
  }
}

// ---------------- attention merge + residual + LN2 partial sums ------------
// qb >= 8 only (qb < 8 finalized inside attn_partial).
__global__ __launch_bounds__(256) void attn_merge_ln(const u16* __restrict__ Opart,
                                                     const float2* __restrict__ ml,
                                                     const float* __restrict__ x,
                                                     float* __restrict__ x2,
                                                     float2* __restrict__ part) {
  const int qb = 8 + (int)blockIdx.x;
  const int bh = blockIdx.y, b = bh >> 4, h = bh & 15;
  const int nc = (qb >> 3) + 1;
  const size_t slot0 = (size_t)bh * 80 + qb_off(qb);
  const int tid = threadIdx.x;
  const int row = tid >> 2, d0 = (tid & 3) * 16;
  __shared__ float red[64][65];

  float wgt[4];
  float mmax = -1e30f, lsum = 0.f;
  for (int i = 0; i < nc; ++i) {
    float2 v = ml[(slot0 + i) * 64 + row];
    wgt[i] = v.x;
    mmax = fmaxf(mmax, v.x);
  }
  for (int i = 0; i < nc; ++i) {
    float2 v = ml[(slot0 + i) * 64 + row];
    wgt[i] = exp2f(wgt[i] - mmax);
    lsum += wgt[i] * v.y;
  }
  const float inv = 1.0f / lsum;

#pragma unroll
  for (int half = 0; half < 2; ++half) {
    const int d = d0 + half * 8;
    float o[8] = {0.f, 0.f, 0.f, 0.f, 0.f, 0.f, 0.f, 0.f};
    for (int i = 0; i < nc; ++i) {
      u16x8 v = *reinterpret_cast<const u16x8*>(&Opart[((slot0 + i) * 64 + row) * 64 + d]);
#pragma unroll
      for (int jj = 0; jj < 8; ++jj) o[jj] += wgt[i] * bf2f(v[jj]);
    }
    const size_t idx = ((size_t)(b * 2048 + qb * 64 + row)) * 1024 + h * 64 + d;
    float4 x0 = *reinterpret_cast<const float4*>(x + idx);
    float4 x1 = *reinterpret_cast<const float4*>(x + idx + 4);
    float4 o0 = make_float4(x0.x + o[0] * inv, x0.y + o[1] * inv, x0.z + o[2] * inv, x0.w + o[3] * inv);
    float4 o1 = make_float4(x1.x + o[4] * inv, x1.y + o[5] * inv, x1.z + o[6] * inv, x1.w + o[7] * inv);
    *reinterpret_cast<float4*>(x2 + idx) = o0;
    *reinterpret_cast<float4*>(x2 + idx + 4) = o1;
    red[row][d + 0] = o0.x; red[row][d + 1] = o0.y; red[row][d + 2] = o0.z; red[row][d + 3] = o0.w;
    red[row][d + 4] = o1.x; red[row][d + 5] = o1.y; red[row][d + 6] = o1.z; red[row][d + 7] = o1.w;
  }
  __syncthreads();
  if (tid < 64) {  // column-reduce over the 64 t-rows
    float s = 0.f, sq = 0.f;
#pragma unroll 8
    for (int t = 0; t < 64; ++t) {
      float v = red[t][tid];
      s += v; sq += v * v;
    }
    part[(size_t)(b * 1024 + h * 64 + tid) * 32 + qb] = make_float2(s, sq);
  }
}

// ---------------------------------------------------------------------------
extern "C" void kernel_launch(void* const* d_in, const int* in_sizes, int n_in,
                              void* d_out, int out_size, void* d_ws, size_t ws_size,
                              hipStream_t stream) {
  const float* x   = (const float*)d_in[0];
  const float* Wq  = (const float*)d_in[1];
  const float* Wk  = (const float*)d_in[2];
  const float* Wv  = (const float*)d_in[3];
  const float* W1  = (const float*)d_in[4];
  const float* b1  = (const float*)d_in[5];
  const float* W2  = (const float*)d_in[6];
  const float* b2  = (const float*)d_in[7];
  const float* g1  = (const float*)d_in[8];
  const float* be1 = (const float*)d_in[9];
  const float* g2  = (const float*)d_in[10];
  const float* be2 = (const float*)d_in[11];
  float* out = (float*)d_out;

  char* ws = (char*)d_ws;
  size_t off = 0;
  auto alloc = [&](size_t bytes) { char* p = ws + off; off += (bytes + 255) & ~(size_t)255; return p; };
  u16*    qkb   = (u16*)alloc(4096ull * 2048 * 2);   // [tok][Q|K]          16MB
  u16*    vtb   = (u16*)alloc(1024ull * 4096 * 2);   // [hd][tok]            8MB
  (void)alloc(4096ull * 1024 * 2);                   // h1 overflow region   8MB
  u16*    h1    = qkb;                               // MLP1 out aliases qk+vt+overflow (32MB)
  float*  x2    = (float*)alloc(4096ull * 1024 * 4); // x + attn            16MB
  u16*    hbuf  = (u16*)alloc(4096ull * 1024 * 2);   // LN outputs           8MB
  u16*    wqkvt = (u16*)alloc(3072ull * 1024 * 2);
  u16*    w1t   = (u16*)alloc(4096ull * 1024 * 2);
  u16*    w2t   = (u16*)alloc(1024ull * 4096 * 2);
  float2* part  = (float2*)alloc(2048ull * 32 * 8);  // LN partials (8 or 32 chunks)
  float2* stats = (float2*)alloc(2048ull * 8);       // (unused, kept for layout)
  u16*    Opart = (u16*)alloc(32ull * 80 * 64 * 64 * 2);   // ~21MB
  float2* ml    = (float2*)alloc(32ull * 80 * 64 * 8);     // ~1.3MB
  (void)ws_size; (void)in_sizes; (void)n_in; (void)out_size; (void)stats;

  // fused prep: weight transposes (Wq scaled by C^-0.5*log2e) + LN1 partials
  const float SC = 0.03125f * 1.44269504088896341f;
  prep_fused<<<3072, 256, 0, stream>>>(Wq, Wk, Wv, W1, W2, x, wqkvt, w1t, w2t, part, SC);

  // LN1: fused stats+apply -> hbuf (bf16)
  ln_stats_apply<8><<<dim3(16, 8, 2), 256, 0, stream>>>(x, part, g1, be1, hbuf);

  // fused QK GEMM (-> qkb [4096][2048]) + V^T GEMM (-> vtb [1024][4096])
  gemm_qkvt<<<768, 256, 0, stream>>>(hbuf, wqkvt, qkb, vtb);

  // attention: split-s partials (nc==1 blocks finalize in-place), then merge
  attn_partial<<<dim3(80, 32), 256, 0, stream>>>(qkb, vtb, x, x2, Opart, ml, part);
  attn_merge_ln<<<dim3(24, 32), 256, 0, stream>>>(Opart, ml, x, x2, part);

  // LN2: fused stats+apply -> hbuf (bf16)
  ln_stats_apply<32><<<dim3(16, 8, 2), 256, 0, stream>>>(x2, part, g2, be2, hbuf);

  // MLP1: relu(h @ W1 + b1) -> h1 (bf16 [4096][4096])   (BN=128)
  gemm_kernel<64, 1, 2><<<dim3(32, 32), 256, 0, stream>>>(hbuf, w1t, h1, nullptr, b1, nullptr, 4096, 1024);

  // MLP2: x2 + h1 @ W2 + b2 -> out (f32)   (BN=64)
  gemm_kernel<32, 2, 3><<<dim3(16, 32), 256, 0, stream>>>(h1, w2t, nullptr, out, b2, x2, 1024, 4096);
}